// Round 5
// baseline (7032.752 us; speedup 1.0000x reference)
//
#include <hip/hip_runtime.h>
#include <cstdint>
#include <cstddef>

typedef unsigned char  u8;
typedef unsigned short u16;
typedef unsigned int   u32;

typedef __attribute__((ext_vector_type(8))) short s16x8;
typedef __attribute__((ext_vector_type(4))) short s16x4;
typedef __attribute__((ext_vector_type(4))) float f32x4;

#define NTILE 4096   // 262144 / 64 rows per tile
#define NBLK  512    // persistent blocks; each does 8 tiles

// ---------------- workspace layout (bytes), total ~19.8 MB ----------------
static const size_t PA_OFF   = 0;          // f32 [4096 tile][512 f] sums
static const size_t PB_OFF   = 8388608;    // f32 [4096][512] sumsq
static const size_t QA_OFF   = 16777216;   // f32 [512 g][512 f] stage-1 sums
static const size_t QB_OFF   = 17825792;   // f32 [512][512]
static const size_t MU_OFF   = 18874368;   // f32 [512]
static const size_t RSTD_OFF = 18876416;   // f32 [512]
static const size_t B1E_OFF  = 18878464;   // f32 [256]
static const size_t WEMB_OFF = 18880512;   // bf16 [3][256][32]
static const size_t WV_OFF   = 18929664;   // bf16 [256][256]
static const size_t W2_OFF   = 19060736;   // bf16 [128][256]
static const size_t W1S_OFF  = 19126272;   // bf16 [256][512] BN-folded
static const size_t WU_OFF   = 19388416;   // f32 [256][256]  Wu = Wq^T Wk
static const size_t G_OFF    = 19650560;   // f32 [2][256][13]
static const size_t GG_OFF   = 19677184;   // f32 [2][256]
static const size_t SCP_OFF  = 19679232;   // f32 [2][256] score params (M,a,b,c)
static const size_t WROW_OFF = 19681280;   // f32 [262144] softmax w1 per row
// end = 20729856

__device__ __forceinline__ u16 f2bf(float f) {
  u32 u = __builtin_bit_cast(u32, f);
  u += 0x7FFFu + ((u >> 16) & 1u);     // RNE
  return (u16)(u >> 16);
}
__device__ __forceinline__ float bf2f(u16 h) {
  u32 u = ((u32)h) << 16;
  return __builtin_bit_cast(float, u);
}

// ---------------- K0: convert weights to bf16 ----------------
__global__ void k0_convert(const float* __restrict__ We,  const float* __restrict__ Wk1,
                           const float* __restrict__ Wk2, const float* __restrict__ Wv,
                           const float* __restrict__ W2,
                           u16* __restrict__ wEmb, u16* __restrict__ wV, u16* __restrict__ wW2)
{
  int i = blockIdx.x * 256 + threadIdx.x;
  if (i < 24576) {                          // padded embeds [agent][h][32]
    int which = i >> 13, rem = i & 8191, h = rem >> 5, c = rem & 31;
    const float* W = (which == 0) ? We : (which == 1) ? Wk1 : Wk2;
    wEmb[i] = (c < 13) ? f2bf(W[h*13 + c]) : (u16)0;
  } else if (i < 24576 + 65536) {           // Wv
    int j = i - 24576;
    wV[j] = f2bf(Wv[j]);
  } else if (i < 24576 + 65536 + 32768) {   // W2
    int j = i - 90112;
    wW2[j] = f2bf(W2[j]);
  }
}

// s_j = Q.K_j = e_q^T Wq^T Wk e_kj ; Wu[a][b] = sum_h Wq[h][a] Wk[h][b]
__global__ void k0b_wu(const float* __restrict__ Wq, const float* __restrict__ Wk,
                       float* __restrict__ Wu)
{
  int a = blockIdx.x, b = threadIdx.x;
  float acc = 0.f;
  #pragma unroll 4
  for (int h = 0; h < 256; ++h)
    acc += Wq[h*256 + a] * Wk[h*256 + b];
  Wu[a*256 + b] = acc;
}

// G_j[a][q] = sum_b Wu[a][b] Wkj[b][q]; g_j[a] = Wu[a][:].bkj
__global__ void k0c_G(const float* __restrict__ Wu,
                      const float* __restrict__ Wk1, const float* __restrict__ bk1,
                      const float* __restrict__ Wk2, const float* __restrict__ bk2,
                      float* __restrict__ G, float* __restrict__ g)
{
  int j = blockIdx.x, a = threadIdx.x;
  const float* Wkj = j ? Wk2 : Wk1;
  const float* bkj = j ? bk2 : bk1;
  float acc[13];
  #pragma unroll
  for (int q = 0; q < 13; ++q) acc[q] = 0.f;
  float ga = 0.f;
  for (int b = 0; b < 256; ++b) {
    float wu = Wu[a*256 + b];
    #pragma unroll
    for (int q = 0; q < 13; ++q) acc[q] += wu * Wkj[b*13 + q];
    ga += wu * bkj[b];
  }
  #pragma unroll
  for (int q = 0; q < 13; ++q) G[j*3328 + a*13 + q] = acc[q];
  g[j*256 + a] = ga;
}

// fold to 13x13 M_j + vectors: scp[j*256+...]: [0..168] M, [169..181] a_p, [182..194] b_q, [195] c
__global__ void k0d_M(const float* __restrict__ We, const float* __restrict__ be,
                      const float* __restrict__ G, const float* __restrict__ g,
                      float* __restrict__ scp)
{
  int j = blockIdx.x, t = threadIdx.x;
  float acc = 0.f;
  if (t < 169) {
    int p = t / 13, q = t - p*13;
    for (int a = 0; a < 256; ++a) acc += We[a*13 + p] * G[j*3328 + a*13 + q];
    scp[j*256 + t] = acc;
  } else if (t < 182) {
    int p = t - 169;
    for (int a = 0; a < 256; ++a) acc += We[a*13 + p] * g[j*256 + a];
    scp[j*256 + t] = acc;
  } else if (t < 195) {
    int q = t - 182;
    for (int a = 0; a < 256; ++a) acc += be[a] * G[j*3328 + a*13 + q];
    scp[j*256 + t] = acc;
  } else if (t == 195) {
    for (int a = 0; a < 256; ++a) acc += be[a] * g[j*256 + a];
    scp[j*256 + 195] = acc;
  }
}

// per-row softmax weight w1 (exact f32 scores)
__global__ __launch_bounds__(256) void k0e_scores(const float* __restrict__ x,
                                                  const float* __restrict__ scp,
                                                  float* __restrict__ wrow)
{
  int row = blockIdx.x * 256 + threadIdx.x;
  const float* xr = x + (size_t)row*39;
  float f0[13], f1[13], f2[13];
  #pragma unroll
  for (int p = 0; p < 12; ++p) { f0[p] = xr[p]; f1[p] = xr[12+p]; f2[p] = xr[24+p]; }
  f0[12] = xr[36]; f1[12] = xr[37]; f2[12] = xr[38];

  auto score = [&](const float* __restrict__ P, const float (&fj)[13]) -> float {
    float s = P[195];
    #pragma unroll
    for (int p = 0; p < 13; ++p) {
      float tp = P[169 + p];
      #pragma unroll
      for (int q = 0; q < 13; ++q) tp += P[p*13 + q] * fj[q];
      s += f0[p] * tp;
    }
    #pragma unroll
    for (int q = 0; q < 13; ++q) s += P[182 + q] * fj[q];
    return s;
  };
  float s1 = score(scp, f1);
  float s2 = score(scp + 256, f2);
  wrow[row] = 1.f / (1.f + __expf((s2 - s1) * 0.0625f));   // /sqrt(256)
}

// ----- xbuf: [64 rows][1024 B], XOR-swizzled by (row&7)<<4; waves touch own rows only -----
template<int NKS>
__device__ __forceinline__ void load_bfrags(const u8* __restrict__ xbuf, int cl, int colbase,
                                            int hi, s16x8* bk)
{
  #pragma unroll
  for (int ks = 0; ks < NKS; ++ks)
    bk[ks] = *(const s16x8*)(xbuf + ((cl*1024 + colbase + ks*64 + hi*16) ^ ((cl & 7) << 4)));
}

template<int NKS, int NM>
__device__ __forceinline__ void wgemmS(const u16* __restrict__ W, int rstride, int coff,
                                       const s16x8* bk, int lr, int hi, f32x4* acc)
{
  #pragma unroll
  for (int ks = 0; ks < NKS; ++ks) {
    #pragma unroll
    for (int m = 0; m < NM; ++m) {
      const s16x8 a = *(const s16x8*)(W + (m*16 + lr)*rstride + coff + ks*32 + hi*8);
      acc[m] = __builtin_amdgcn_mfma_f32_16x16x32_bf16(a, bk[ks], acc[m], 0, 0, 0);
    }
  }
}

// embed GEMM (K=32 padded), streamed per-m store into xbuf half (bias added)
__device__ __forceinline__ void egemm_store(const u16* __restrict__ Wj, s16x8 b,
                                            const float* __restrict__ bias,
                                            u8* __restrict__ xbuf, int colbase,
                                            int cl, int lr, int hi)
{
  #pragma unroll
  for (int m = 0; m < 16; ++m) {
    const s16x8 a = *(const s16x8*)(Wj + (m*16 + lr)*32 + hi*8);
    f32x4 k4 = {0.f, 0.f, 0.f, 0.f};
    k4 = __builtin_amdgcn_mfma_f32_16x16x32_bf16(a, b, k4, 0, 0, 0);
    f32x4 bb = ((const f32x4*)bias)[m*4 + hi];
    s16x4 p;
    #pragma unroll
    for (int r = 0; r < 4; ++r) p[r] = (short)f2bf(k4[r] + bb[r]);
    *(s16x4*)(xbuf + ((cl*1024 + colbase + m*32 + hi*8) ^ ((cl & 7) << 4))) = p;
  }
}

// streaming V GEMM: per-m 8 MFMA -> bias+leaky -> weighted accumulate (no 2nd array)
template<bool INIT>
__device__ __forceinline__ void vstream(const u16* __restrict__ W, const s16x8* bk,
                                        int lr, int hi, const float* __restrict__ bv,
                                        float w, f32x4* vacc)
{
  #pragma unroll
  for (int m = 0; m < 16; ++m) {
    f32x4 v4 = {0.f, 0.f, 0.f, 0.f};
    #pragma unroll
    for (int ks = 0; ks < 8; ++ks) {
      const s16x8 a = *(const s16x8*)(W + (m*16 + lr)*256 + ks*32 + hi*8);
      v4 = __builtin_amdgcn_mfma_f32_16x16x32_bf16(a, bk[ks], v4, 0, 0, 0);
    }
    f32x4 bb = ((const f32x4*)bv)[m*4 + hi];
    #pragma unroll
    for (int r = 0; r < 4; ++r) {
      float v = v4[r] + bb[r];
      v = (v > 0.f) ? v : 0.01f*v;
      if (INIT) vacc[m][r] = w * v;
      else      vacc[m][r] += w * v;
    }
  }
}

template<bool HASB, bool RELU, int NM>
__device__ __forceinline__ void store_half(u8* __restrict__ xbuf, int colbase, const f32x4* acc,
                                           const float* __restrict__ bias, int cl, int hi)
{
  #pragma unroll
  for (int m = 0; m < NM; ++m) {
    f32x4 bb = {0.f, 0.f, 0.f, 0.f};
    if (HASB) bb = ((const f32x4*)bias)[m*4 + hi];
    s16x4 p;
    #pragma unroll
    for (int r = 0; r < 4; ++r) {
      float v = acc[m][r] + bb[r];
      if (RELU) v = (v > 0.f) ? v : 0.f;
      p[r] = (short)f2bf(v);
    }
    *(s16x4*)(xbuf + ((cl*1024 + colbase + m*32 + hi*8) ^ ((cl & 7) << 4))) = p;
  }
}

__device__ __forceinline__ s16x8 make_bfr(const float* __restrict__ xr, int a, int hi)
{
  s16x8 v = {0,0,0,0,0,0,0,0};
  if (hi == 0) {
    #pragma unroll
    for (int e = 0; e < 8; ++e) v[e] = (short)f2bf(xr[12*a + e]);
  } else if (hi == 1) {
    #pragma unroll
    for (int e = 0; e < 4; ++e) v[e] = (short)f2bf(xr[12*a + 8 + e]);
    v[4] = (short)f2bf(xr[36 + a]);   // action column -> padded slot 12
  }
  return v;
}

// ---- attention tile: fills xbuf rows [e_q | atten], barrier-free, ~115 live VGPRs ----
__device__ __forceinline__ void attn_tile(
    const float* __restrict__ x, int rowbase,
    const u16* __restrict__ wEmb, const float* __restrict__ be,
    const float* __restrict__ bk1, const float* __restrict__ bk2,
    const u16* __restrict__ wV, const float* __restrict__ bv,
    const float* __restrict__ wrow,
    u8* __restrict__ xbuf, int cl, int lr, int hi)
{
  const float w1 = wrow[rowbase + cl];
  const float w2 = 1.f - w1;
  const float* xr = x + (size_t)(rowbase + cl)*39;

  // e_q -> bytes 0..511
  egemm_store(wEmb, make_bfr(xr, 0, hi), be, xbuf, 0, cl, lr, hi);
  // e_k1 -> bytes 512..1023
  egemm_store(wEmb + 8192, make_bfr(xr, 1, hi), bk1, xbuf, 512, cl, lr, hi);

  s16x8 bk[8];
  f32x4 vacc[16];
  load_bfrags<8>(xbuf, cl, 512, hi, bk);
  vstream<true>(wV, bk, lr, hi, bv, w1, vacc);       // V1, weighted w1

  // e_k2 overwrites work half (bk regs already hold e_k1; own-rows only)
  egemm_store(wEmb + 16384, make_bfr(xr, 2, hi), bk2, xbuf, 512, cl, lr, hi);
  load_bfrags<8>(xbuf, cl, 512, hi, bk);
  vstream<false>(wV, bk, lr, hi, bv, w2, vacc);      // V2, weighted w2

  // atten -> bytes 512..1023
  store_half<false, false, 16>(xbuf, 512, vacc, nullptr, cl, hi);
}

// ---------------- K1: persistent attention pass -> BN partial sums ----------------
__global__ __launch_bounds__(256) __attribute__((amdgpu_waves_per_eu(1, 2)))
void k1_attn(
    const float* __restrict__ x,
    const u16* __restrict__ wEmb, const float* __restrict__ be,
    const float* __restrict__ bk1, const float* __restrict__ bk2,
    const u16* __restrict__ wV, const float* __restrict__ bv,
    const float* __restrict__ wrow,
    float* __restrict__ pA, float* __restrict__ pB)
{
  __shared__ __align__(16) u8 xbuf[65536];
  const int t = threadIdx.x;
  const int lane = t & 63;
  const int wv_ = t >> 6;
  const int lr = lane & 15, hi = lane >> 4;
  const int cl = wv_*16 + lr;

  for (int wt = blockIdx.x; wt < NTILE; wt += NBLK) {
    const int rowbase = wt * 64;
    attn_tile(x, rowbase, wEmb, be, bk1, bk2, wV, bv, wrow, xbuf, cl, lr, hi);
    __syncthreads();   // cross-row consumer below

    // BN partials: thread t owns features 2t, 2t+1 across all 64 rows
    float s0 = 0.f, q0 = 0.f, s1 = 0.f, q1 = 0.f;
    for (int r = 0; r < 64; ++r) {
      u32 v = *(const u32*)(xbuf + ((r*1024 + t*4) ^ ((r & 7) << 4)));
      float a = bf2f((u16)(v & 0xFFFFu));
      float b = bf2f((u16)(v >> 16));
      s0 += a; q0 += a*a; s1 += b; q1 += b*b;
    }
    *(float2*)(pA + (size_t)wt*512 + 2*t) = make_float2(s0, s1);
    *(float2*)(pB + (size_t)wt*512 + 2*t) = make_float2(q0, q1);
    __syncthreads();   // next tile overwrites xbuf
  }
}

// ---------------- KR1: stage-1 reduce (coalesced): 4096 tiles -> 512 groups ----------------
__global__ void kR1_reduce(const float* __restrict__ pA, const float* __restrict__ pB,
                           float* __restrict__ qA, float* __restrict__ qB)
{
  int g = blockIdx.x, t = threadIdx.x;   // 512 x 256
  float2 sA = make_float2(0.f, 0.f), sB = make_float2(0.f, 0.f);
  #pragma unroll
  for (int k = 0; k < 8; ++k) {
    size_t wg = (size_t)g*8 + k;
    float2 a = *(const float2*)(pA + wg*512 + 2*t);
    float2 b = *(const float2*)(pB + wg*512 + 2*t);
    sA.x += a.x; sA.y += a.y; sB.x += b.x; sB.y += b.y;
  }
  *(float2*)(qA + (size_t)g*512 + 2*t) = sA;
  *(float2*)(qB + (size_t)g*512 + 2*t) = sB;
}

// ---------------- KR2: final reduce -> mu, rstd ----------------
__global__ void kR2_stats(const float* __restrict__ qA, const float* __restrict__ qB,
                          float* __restrict__ mu, float* __restrict__ rstd)
{
  int f = blockIdx.x, t = threadIdx.x;   // 512 blocks x 256 threads
  float s = 0.f, q = 0.f;
  #pragma unroll
  for (int k = 0; k < 2; ++k) {
    int g = t + k*256;
    s += qA[(size_t)g*512 + f];
    q += qB[(size_t)g*512 + f];
  }
  #pragma unroll
  for (int off = 1; off < 64; off <<= 1) {
    s += __shfl_xor(s, off);
    q += __shfl_xor(q, off);
  }
  __shared__ float ls[4], lq[4];
  if ((t & 63) == 0) { ls[t >> 6] = s; lq[t >> 6] = q; }
  __syncthreads();
  if (t == 0) {
    float S = ls[0]+ls[1]+ls[2]+ls[3];
    float Q = lq[0]+lq[1]+lq[2]+lq[3];
    float m = S * (1.f/262144.f);
    float v = Q * (1.f/262144.f) - m*m;   // biased variance
    mu[f] = m;
    rstd[f] = 1.f / sqrtf(v + 1e-5f);
  }
}

// ---------------- K2b: fold BN into W1 ----------------
__global__ void k2b_fold(const float* __restrict__ W1, const float* __restrict__ b1,
                         const float* __restrict__ mu, const float* __restrict__ rstd,
                         u16* __restrict__ W1s, float* __restrict__ b1eff)
{
  int o = blockIdx.x, t = threadIdx.x;   // 256 blocks x 256 threads
  float local = 0.f;
  #pragma unroll
  for (int k = 0; k < 2; ++k) {
    int f = t + k*256;
    float w = W1[o*512 + f];
    float r = rstd[f];
    W1s[o*512 + f] = f2bf(w * r);
    local += w * r * mu[f];
  }
  #pragma unroll
  for (int off = 1; off < 64; off <<= 1) local += __shfl_xor(local, off);
  __shared__ float ls[4];
  if ((t & 63) == 0) ls[t >> 6] = local;
  __syncthreads();
  if (t == 0) b1eff[o] = b1[o] - (ls[0]+ls[1]+ls[2]+ls[3]);
}

// ---------------- K3: persistent attention recompute + MLP head ----------------
__global__ __launch_bounds__(256) __attribute__((amdgpu_waves_per_eu(1, 2)))
void k3_mlp(
    const float* __restrict__ x,
    const u16* __restrict__ wEmb, const float* __restrict__ be,
    const float* __restrict__ bk1, const float* __restrict__ bk2,
    const u16* __restrict__ wV, const float* __restrict__ bv,
    const float* __restrict__ wrow,
    const u16* __restrict__ W1s, const float* __restrict__ b1eff,
    const u16* __restrict__ wW2, const float* __restrict__ b2,
    const float* __restrict__ W3, const float* __restrict__ b3,
    float* __restrict__ out)
{
  __shared__ __align__(16) u8 xbuf[65536];
  const int t = threadIdx.x;
  const int lane = t & 63;
  const int wv_ = t >> 6;
  const int lr = lane & 15, hi = lane >> 4;
  const int cl = wv_*16 + lr;
  const f32x4 zero4 = {0.f, 0.f, 0.f, 0.f};

  for (int wt = blockIdx.x; wt < NTILE; wt += NBLK) {
    const int rowbase = wt * 64;
    attn_tile(x, rowbase, wEmb, be, bk1, bk2, wV, bv, wrow, xbuf, cl, lr, hi);

    // GEMM1: h1 = relu(X @ W1s.T + b1eff), K=512 in two 8-frag halves (own rows only)
    f32x4 acc[16];
    #pragma unroll
    for (int m = 0; m < 16; ++m) acc[m] = zero4;
    {
      s16x8 bk[8];
      load_bfrags<8>(xbuf, cl, 0, hi, bk);
      wgemmS<8, 16>(W1s, 512, 0, bk, lr, hi, acc);
      load_bfrags<8>(xbuf, cl, 512, hi, bk);
      wgemmS<8, 16>(W1s, 512, 256, bk, lr, hi, acc);
    }
    store_half<true, true, 16>(xbuf, 0, acc, b1eff, cl, hi);   // h1 -> bytes 0..511

    // GEMM2: h2 = relu(h1 @ W2.T + b2), K=256 (own rows only)
    f32x4 acc2[8];
    #pragma unroll
    for (int m = 0; m < 8; ++m) acc2[m] = zero4;
    {
      s16x8 bk[8];
      load_bfrags<8>(xbuf, cl, 0, hi, bk);
      wgemmS<8, 8>(wW2, 256, 0, bk, lr, hi, acc2);
    }
    store_half<true, true, 8>(xbuf, 512, acc2, b2, cl, hi);    // h2 -> bytes 512..767
    __syncthreads();   // cross-row consumer below

    // out = h2 @ W3.T + b3 (one thread per row)
    if (t < 64) {
      float s = b3[0];
      #pragma unroll
      for (int jj = 0; jj < 16; ++jj) {
        const u32* v = (const u32*)(xbuf + ((t*1024 + 512 + jj*16) ^ ((t & 7) << 4)));
        #pragma unroll
        for (int q2 = 0; q2 < 4; ++q2) {
          u32 u = v[q2];
          s += bf2f((u16)(u & 0xFFFFu)) * W3[jj*8 + q2*2];
          s += bf2f((u16)(u >> 16))     * W3[jj*8 + q2*2 + 1];
        }
      }
      out[rowbase + t] = s;
    }
    __syncthreads();   // next tile overwrites xbuf
  }
}

extern "C" void kernel_launch(void* const* d_in, const int* in_sizes, int n_in,
                              void* d_out, int out_size, void* d_ws, size_t ws_size,
                              hipStream_t stream)
{
  const float* x   = (const float*)d_in[0];
  const float* We  = (const float*)d_in[1];
  const float* be  = (const float*)d_in[2];
  const float* Wk1 = (const float*)d_in[3];
  const float* bk1 = (const float*)d_in[4];
  const float* Wk2 = (const float*)d_in[5];
  const float* bk2 = (const float*)d_in[6];
  const float* Wq  = (const float*)d_in[7];
  const float* Wk  = (const float*)d_in[8];
  const float* Wv  = (const float*)d_in[9];
  const float* bv  = (const float*)d_in[10];
  const float* W1  = (const float*)d_in[11];
  const float* b1  = (const float*)d_in[12];
  const float* W2  = (const float*)d_in[13];
  const float* b2  = (const float*)d_in[14];
  const float* W3  = (const float*)d_in[15];
  const float* b3  = (const float*)d_in[16];

  u8* ws = (u8*)d_ws;
  float* pA    = (float*)(ws + PA_OFF);
  float* pB    = (float*)(ws + PB_OFF);
  float* qA    = (float*)(ws + QA_OFF);
  float* qB    = (float*)(ws + QB_OFF);
  float* mu    = (float*)(ws + MU_OFF);
  float* rstd  = (float*)(ws + RSTD_OFF);
  float* b1eff = (float*)(ws + B1E_OFF);
  u16*   wEmb  = (u16*)(ws + WEMB_OFF);
  u16*   wVb   = (u16*)(ws + WV_OFF);
  u16*   wW2   = (u16*)(ws + W2_OFF);
  u16*   wW1s  = (u16*)(ws + W1S_OFF);
  float* Wu    = (float*)(ws + WU_OFF);
  float* G     = (float*)(ws + G_OFF);
  float* g     = (float*)(ws + GG_OFF);
  float* scp   = (float*)(ws + SCP_OFF);
  float* wrow  = (float*)(ws + WROW_OFF);

  k0_convert<<<dim3(480), dim3(256), 0, stream>>>(We, Wk1, Wk2, Wv, W2, wEmb, wVb, wW2);
  k0b_wu<<<dim3(256), dim3(256), 0, stream>>>(Wq, Wk, Wu);
  k0c_G<<<dim3(2), dim3(256), 0, stream>>>(Wu, Wk1, bk1, Wk2, bk2, G, g);
  k0d_M<<<dim3(2), dim3(256), 0, stream>>>(We, be, G, g, scp);
  k0e_scores<<<dim3(1024), dim3(256), 0, stream>>>(x, scp, wrow);
  k1_attn<<<dim3(NBLK), dim3(256), 0, stream>>>(x, wEmb, be, bk1, bk2, wVb, bv, wrow, pA, pB);
  kR1_reduce<<<dim3(512), dim3(256), 0, stream>>>(pA, pB, qA, qB);
  kR2_stats<<<dim3(512), dim3(256), 0, stream>>>(qA, qB, mu, rstd);
  k2b_fold<<<dim3(256), dim3(256), 0, stream>>>(W1, b1, mu, rstd, wW1s, b1eff);
  k3_mlp<<<dim3(NBLK), dim3(256), 0, stream>>>(x, wEmb, be, bk1, bk2, wVb, bv, wrow,
                                               wW1s, b1eff, wW2, b2, W3, b3,
                                               (float*)d_out);
}

// Round 6
// 604.015 us; speedup vs baseline: 11.6433x; 11.6433x over previous
//
#include <hip/hip_runtime.h>
#include <cstdint>
#include <cstddef>

typedef unsigned char  u8;
typedef unsigned short u16;
typedef unsigned int   u32;

typedef __attribute__((ext_vector_type(8))) short s16x8;
typedef __attribute__((ext_vector_type(4))) short s16x4;
typedef __attribute__((ext_vector_type(4))) float f32x4;
typedef __attribute__((ext_vector_type(4))) u32   u32x4;

#define NTILE 4096   // 262144 / 64 rows per tile

// LDS regions (bytes): 3 x 32KB activation + 64KB weight stage = 160KB
#define EQ_R 0
#define K1_R 32768
#define K2_R 65536
#define WB_O 98304
#define SMEM_BYTES 163840

// ---------------- workspace layout (bytes), total ~19.8 MB ----------------
static const size_t PA_OFF   = 0;          // f32 [4096 tile][512 f] sums
static const size_t PB_OFF   = 8388608;    // f32 [4096][512] sumsq
static const size_t QA_OFF   = 16777216;   // f32 [512 g][512 f] stage-1 sums
static const size_t QB_OFF   = 17825792;   // f32 [512][512]
static const size_t MU_OFF   = 18874368;   // f32 [512]
static const size_t RSTD_OFF = 18876416;   // f32 [512]
static const size_t B1E_OFF  = 18878464;   // f32 [256]
static const size_t WEMB_OFF = 18880512;   // bf16 [3][256][32]
static const size_t WV_OFF   = 18929664;   // bf16 [256][256]
static const size_t W2_OFF   = 19060736;   // bf16 [128][256]
static const size_t W1S_OFF  = 19126272;   // bf16 [256][512] BN-folded
static const size_t WU_OFF   = 19388416;   // f32 [256][256]  Wu = Wq^T Wk
static const size_t G_OFF    = 19650560;   // f32 [2][256][13]
static const size_t GG_OFF   = 19677184;   // f32 [2][256]
static const size_t SCP_OFF  = 19679232;   // f32 [2][256] score params
static const size_t WROW_OFF = 19681280;   // f32 [262144] softmax w1 per row
// end = 20729856

__device__ __forceinline__ u16 f2bf(float f) {
  u32 u = __builtin_bit_cast(u32, f);
  u += 0x7FFFu + ((u >> 16) & 1u);     // RNE
  return (u16)(u >> 16);
}
__device__ __forceinline__ float bf2f(u16 h) {
  u32 u = ((u32)h) << 16;
  return __builtin_bit_cast(float, u);
}

// ---------------- K0: convert weights to bf16 ----------------
__global__ void k0_convert(const float* __restrict__ We,  const float* __restrict__ Wk1,
                           const float* __restrict__ Wk2, const float* __restrict__ Wv,
                           const float* __restrict__ W2,
                           u16* __restrict__ wEmb, u16* __restrict__ wV, u16* __restrict__ wW2)
{
  int i = blockIdx.x * 256 + threadIdx.x;
  if (i < 24576) {                          // padded embeds [agent][h][32]
    int which = i >> 13, rem = i & 8191, h = rem >> 5, c = rem & 31;
    const float* W = (which == 0) ? We : (which == 1) ? Wk1 : Wk2;
    wEmb[i] = (c < 13) ? f2bf(W[h*13 + c]) : (u16)0;
  } else if (i < 24576 + 65536) {           // Wv
    int j = i - 24576;
    wV[j] = f2bf(Wv[j]);
  } else if (i < 24576 + 65536 + 32768) {   // W2
    int j = i - 90112;
    wW2[j] = f2bf(W2[j]);
  }
}

// s_j = e_q^T Wq^T Wk e_kj ; Wu[a][b] = sum_h Wq[h][a] Wk[h][b]
__global__ void k0b_wu(const float* __restrict__ Wq, const float* __restrict__ Wk,
                       float* __restrict__ Wu)
{
  int a = blockIdx.x, b = threadIdx.x;
  float acc = 0.f;
  #pragma unroll 4
  for (int h = 0; h < 256; ++h)
    acc += Wq[h*256 + a] * Wk[h*256 + b];
  Wu[a*256 + b] = acc;
}

__global__ void k0c_G(const float* __restrict__ Wu,
                      const float* __restrict__ Wk1, const float* __restrict__ bk1,
                      const float* __restrict__ Wk2, const float* __restrict__ bk2,
                      float* __restrict__ G, float* __restrict__ g)
{
  int j = blockIdx.x, a = threadIdx.x;
  const float* Wkj = j ? Wk2 : Wk1;
  const float* bkj = j ? bk2 : bk1;
  float acc[13];
  #pragma unroll
  for (int q = 0; q < 13; ++q) acc[q] = 0.f;
  float ga = 0.f;
  for (int b = 0; b < 256; ++b) {
    float wu = Wu[a*256 + b];
    #pragma unroll
    for (int q = 0; q < 13; ++q) acc[q] += wu * Wkj[b*13 + q];
    ga += wu * bkj[b];
  }
  #pragma unroll
  for (int q = 0; q < 13; ++q) G[j*3328 + a*13 + q] = acc[q];
  g[j*256 + a] = ga;
}

__global__ void k0d_M(const float* __restrict__ We, const float* __restrict__ be,
                      const float* __restrict__ G, const float* __restrict__ g,
                      float* __restrict__ scp)
{
  int j = blockIdx.x, t = threadIdx.x;
  float acc = 0.f;
  if (t < 169) {
    int p = t / 13, q = t - p*13;
    for (int a = 0; a < 256; ++a) acc += We[a*13 + p] * G[j*3328 + a*13 + q];
    scp[j*256 + t] = acc;
  } else if (t < 182) {
    int p = t - 169;
    for (int a = 0; a < 256; ++a) acc += We[a*13 + p] * g[j*256 + a];
    scp[j*256 + t] = acc;
  } else if (t < 195) {
    int q = t - 182;
    for (int a = 0; a < 256; ++a) acc += be[a] * G[j*3328 + a*13 + q];
    scp[j*256 + t] = acc;
  } else if (t == 195) {
    for (int a = 0; a < 256; ++a) acc += be[a] * g[j*256 + a];
    scp[j*256 + 195] = acc;
  }
}

__global__ __launch_bounds__(256) void k0e_scores(const float* __restrict__ x,
                                                  const float* __restrict__ scp,
                                                  float* __restrict__ wrow)
{
  int row = blockIdx.x * 256 + threadIdx.x;
  const float* xr = x + (size_t)row*39;
  float f0[13], f1[13], f2[13];
  #pragma unroll
  for (int p = 0; p < 12; ++p) { f0[p] = xr[p]; f1[p] = xr[12+p]; f2[p] = xr[24+p]; }
  f0[12] = xr[36]; f1[12] = xr[37]; f2[12] = xr[38];

  auto score = [&](const float* __restrict__ P, const float (&fj)[13]) -> float {
    float s = P[195];
    #pragma unroll
    for (int p = 0; p < 13; ++p) {
      float tp = P[169 + p];
      #pragma unroll
      for (int q = 0; q < 13; ++q) tp += P[p*13 + q] * fj[q];
      s += f0[p] * tp;
    }
    #pragma unroll
    for (int q = 0; q < 13; ++q) s += P[182 + q] * fj[q];
    return s;
  };
  float s1 = score(scp, f1);
  float s2 = score(scp + 256, f2);
  wrow[row] = 1.f / (1.f + __expf((s2 - s1) * 0.0625f));   // /sqrt(256)
}

// ---------------- LDS staging (512 threads) ----------------
// weight half [128 rows][256 cols] bf16 -> WB, swizzle ((row&7)<<4)
__device__ __forceinline__ void stage_w128(u8* __restrict__ smem, const u16* __restrict__ src,
                                           int srcStride, int t)
{
  #pragma unroll
  for (int i = 0; i < 8; ++i) {
    int u = t + i*512;
    int row = u >> 5, cu = u & 31;
    s16x8 v = *(const s16x8*)(src + row*srcStride + cu*8);
    *(s16x8*)(smem + WB_O + ((row*512 + cu*16) ^ ((row & 7) << 4))) = v;
  }
}
// embeds [768 rows][32 cols] bf16 -> WB, swizzle ((row&3)<<4)
__device__ __forceinline__ void stage_emb(u8* __restrict__ smem, const u16* __restrict__ wEmb,
                                          int t)
{
  #pragma unroll
  for (int i = 0; i < 6; ++i) {
    int u = t + i*512;
    int row = u >> 2, cu = u & 3;
    s16x8 v = *(const s16x8*)(wEmb + row*32 + cu*8);
    *(s16x8*)(smem + WB_O + ((row*64 + cu*16) ^ ((row & 3) << 4))) = v;
  }
}

// ---------------- LDS accessors ----------------
__device__ __forceinline__ s16x8 ldsA(const u8* __restrict__ smem, int row, int ks, int hi) {
  return *(const s16x8*)(smem + WB_O + ((row*512 + ks*64 + hi*16) ^ ((row & 7) << 4)));
}
__device__ __forceinline__ s16x8 ldsAe(const u8* __restrict__ smem, int row, int hi) {
  return *(const s16x8*)(smem + WB_O + ((row*64 + hi*16) ^ ((row & 3) << 4)));
}
__device__ __forceinline__ s16x8 ldsB(const u8* __restrict__ smem, int reg, int col, int ks, int hi) {
  return *(const s16x8*)(smem + reg + ((col*512 + ks*64 + hi*16) ^ ((col & 7) << 4)));
}

__device__ __forceinline__ s16x8 make_bfr(const float* __restrict__ xr, int a, int hi)
{
  s16x8 v = {0,0,0,0,0,0,0,0};
  if (hi == 0) {
    #pragma unroll
    for (int e = 0; e < 8; ++e) v[e] = (short)f2bf(xr[12*a + e]);
  } else if (hi == 1) {
    #pragma unroll
    for (int e = 0; e < 4; ++e) v[e] = (short)f2bf(xr[12*a + 8 + e]);
    v[4] = (short)f2bf(xr[36 + a]);   // action column -> padded slot 12
  }
  return v;
}

// embed GEMM: wave group mg computes feats [mg*128, +128) for its 16 cols
__device__ __forceinline__ void embed_one(u8* __restrict__ smem, int reg, int agent,
                                          const float* __restrict__ bias, s16x8 b,
                                          int cl, int lr, int hi, int mg)
{
  #pragma unroll
  for (int m = 0; m < 8; ++m) {
    int row = agent*256 + mg*128 + m*16 + lr;
    f32x4 k4 = {0.f, 0.f, 0.f, 0.f};
    k4 = __builtin_amdgcn_mfma_f32_16x16x32_bf16(ldsAe(smem, row, hi), b, k4, 0, 0, 0);
    f32x4 bb = ((const f32x4*)bias)[mg*32 + m*4 + hi];
    s16x4 p;
    #pragma unroll
    for (int r = 0; r < 4; ++r) p[r] = (short)f2bf(k4[r] + bb[r]);
    *(s16x4*)(smem + reg + ((cl*512 + mg*256 + m*32 + hi*8) ^ ((cl & 7) << 4))) = p;
  }
}

// ---- shared attention phase: ends with e_q in EQ_R, atten in K1_R; smem-barrier'd ----
__device__ __forceinline__ void attn_phase(
    u8* __restrict__ smem, const float* __restrict__ x, int rowbase,
    const u16* __restrict__ wEmb, const float* __restrict__ be,
    const float* __restrict__ bk1, const float* __restrict__ bk2,
    const u16* __restrict__ wV, const float* __restrict__ bv,
    const float* __restrict__ wrow,
    int t, int cl, int lr, int hi, int mg)
{
  const float w1 = wrow[rowbase + cl];
  const float w2 = 1.f - w1;
  const float* xr = x + (size_t)(rowbase + cl)*39;
  s16x8 bfr0 = make_bfr(xr, 0, hi);
  s16x8 bfr1 = make_bfr(xr, 1, hi);
  s16x8 bfr2 = make_bfr(xr, 2, hi);

  stage_emb(smem, wEmb, t);
  __syncthreads();
  embed_one(smem, EQ_R, 0, be,  bfr0, cl, lr, hi, mg);
  embed_one(smem, K1_R, 1, bk1, bfr1, cl, lr, hi, mg);
  embed_one(smem, K2_R, 2, bk2, bfr2, cl, lr, hi, mg);
  __syncthreads();

  s16x4 att[2][4];
  #pragma unroll
  for (int oh = 0; oh < 2; ++oh) {
    stage_w128(smem, wV + oh*32768, 256, t);
    __syncthreads();
    f32x4 a1[4], a2[4];
    #pragma unroll
    for (int m = 0; m < 4; ++m) { a1[m] = {0.f,0.f,0.f,0.f}; a2[m] = {0.f,0.f,0.f,0.f}; }
    #pragma unroll
    for (int ks = 0; ks < 8; ++ks) {
      s16x8 b1 = ldsB(smem, K1_R, cl, ks, hi);
      s16x8 b2 = ldsB(smem, K2_R, cl, ks, hi);
      #pragma unroll
      for (int m = 0; m < 4; ++m) {
        s16x8 a = ldsA(smem, mg*64 + m*16 + lr, ks, hi);
        a1[m] = __builtin_amdgcn_mfma_f32_16x16x32_bf16(a, b1, a1[m], 0, 0, 0);
        a2[m] = __builtin_amdgcn_mfma_f32_16x16x32_bf16(a, b2, a2[m], 0, 0, 0);
      }
    }
    __syncthreads();   // wbuf + k1/k2 reads done before next stage / att write
    #pragma unroll
    for (int m = 0; m < 4; ++m) {
      f32x4 bb = ((const f32x4*)bv)[oh*32 + mg*16 + m*4 + hi];
      s16x4 p;
      #pragma unroll
      for (int r = 0; r < 4; ++r) {
        float va = a1[m][r] + bb[r]; va = (va > 0.f) ? va : 0.01f*va;
        float vb = a2[m][r] + bb[r]; vb = (vb > 0.f) ? vb : 0.01f*vb;
        p[r] = (short)f2bf(w1*va + w2*vb);
      }
      att[oh][m] = p;
    }
  }
  // atten -> K1 region (e_k1 dead)
  #pragma unroll
  for (int oh = 0; oh < 2; ++oh)
    #pragma unroll
    for (int m = 0; m < 4; ++m)
      *(s16x4*)(smem + K1_R + ((cl*512 + oh*256 + mg*128 + m*32 + hi*8) ^ ((cl & 7) << 4)))
          = att[oh][m];
  __syncthreads();
}

// ---------------- K1: attention pass -> BN partial sums ----------------
__global__ __launch_bounds__(512, 1) void k1_attn(
    const float* __restrict__ x,
    const u16* __restrict__ wEmb, const float* __restrict__ be,
    const float* __restrict__ bk1, const float* __restrict__ bk2,
    const u16* __restrict__ wV, const float* __restrict__ bv,
    const float* __restrict__ wrow,
    float* __restrict__ pA, float* __restrict__ pB)
{
  __shared__ __align__(16) u8 smem[SMEM_BYTES];
  const int t = threadIdx.x;
  const int wt = blockIdx.x;
  const int rowbase = wt * 64;
  const int lane = t & 63;
  const int wv_ = t >> 6;
  const int colg = wv_ & 3, mg = wv_ >> 2;
  const int lr = lane & 15, hi = lane >> 4;
  const int cl = colg*16 + lr;

  attn_phase(smem, x, rowbase, wEmb, be, bk1, bk2, wV, bv, wrow, t, cl, lr, hi, mg);

  // BN partials: thread t owns global feature t (t<256: e_q, else atten)
  const int fl = t & 255;
  const int reg = (t < 256) ? EQ_R : K1_R;
  float s = 0.f, q = 0.f;
  for (int c = 0; c < 64; ++c) {
    u16 v = *(const u16*)(smem + reg + ((c*512 + fl*2) ^ ((c & 7) << 4)));
    float a = bf2f(v);
    s += a; q += a*a;
  }
  pA[(size_t)wt*512 + t] = s;
  pB[(size_t)wt*512 + t] = q;
}

// ---------------- KR1: stage-1 reduce: 4096 tiles -> 512 groups ----------------
__global__ void kR1_reduce(const float* __restrict__ pA, const float* __restrict__ pB,
                           float* __restrict__ qA, float* __restrict__ qB)
{
  int g = blockIdx.x, t = threadIdx.x;   // 512 x 256
  float2 sA = make_float2(0.f, 0.f), sB = make_float2(0.f, 0.f);
  #pragma unroll
  for (int k = 0; k < 8; ++k) {
    size_t wg = (size_t)g*8 + k;
    float2 a = *(const float2*)(pA + wg*512 + 2*t);
    float2 b = *(const float2*)(pB + wg*512 + 2*t);
    sA.x += a.x; sA.y += a.y; sB.x += b.x; sB.y += b.y;
  }
  *(float2*)(qA + (size_t)g*512 + 2*t) = sA;
  *(float2*)(qB + (size_t)g*512 + 2*t) = sB;
}

// ---------------- KR2: final reduce -> mu, rstd ----------------
__global__ void kR2_stats(const float* __restrict__ qA, const float* __restrict__ qB,
                          float* __restrict__ mu, float* __restrict__ rstd)
{
  int f = blockIdx.x, t = threadIdx.x;   // 512 blocks x 256 threads
  float s = 0.f, q = 0.f;
  #pragma unroll
  for (int k = 0; k < 2; ++k) {
    int g = t + k*256;
    s += qA[(size_t)g*512 + f];
    q += qB[(size_t)g*512 + f];
  }
  #pragma unroll
  for (int off = 1; off < 64; off <<= 1) {
    s += __shfl_xor(s, off);
    q += __shfl_xor(q, off);
  }
  __shared__ float ls[4], lq[4];
  if ((t & 63) == 0) { ls[t >> 6] = s; lq[t >> 6] = q; }
  __syncthreads();
  if (t == 0) {
    float S = ls[0]+ls[1]+ls[2]+ls[3];
    float Q = lq[0]+lq[1]+lq[2]+lq[3];
    float m = S * (1.f/262144.f);
    float v = Q * (1.f/262144.f) - m*m;   // biased variance
    mu[f] = m;
    rstd[f] = 1.f / sqrtf(v + 1e-5f);
  }
}

// ---------------- K2b: fold BN into W1 ----------------
__global__ void k2b_fold(const float* __restrict__ W1, const float* __restrict__ b1,
                         const float* __restrict__ mu, const float* __restrict__ rstd,
                         u16* __restrict__ W1s, float* __restrict__ b1eff)
{
  int o = blockIdx.x, t = threadIdx.x;   // 256 blocks x 256 threads
  float local = 0.f;
  #pragma unroll
  for (int k = 0; k < 2; ++k) {
    int f = t + k*256;
    float w = W1[o*512 + f];
    float r = rstd[f];
    W1s[o*512 + f] = f2bf(w * r);
    local += w * r * mu[f];
  }
  #pragma unroll
  for (int off = 1; off < 64; off <<= 1) local += __shfl_xor(local, off);
  __shared__ float ls[4];
  if ((t & 63) == 0) ls[t >> 6] = local;
  __syncthreads();
  if (t == 0) b1eff[o] = b1[o] - (ls[0]+ls[1]+ls[2]+ls[3]);
}

// ---------------- K3: attention recompute + MLP head ----------------
__global__ __launch_bounds__(512, 1) void k3_mlp(
    const float* __restrict__ x,
    const u16* __restrict__ wEmb, const float* __restrict__ be,
    const float* __restrict__ bk1, const float* __restrict__ bk2,
    const u16* __restrict__ wV, const float* __restrict__ bv,
    const float* __restrict__ wrow,
    const u16* __restrict__ W1s, const float* __restrict__ b1eff,
    const u16* __restrict__ wW2, const float* __restrict__ b2,
    const float* __restrict__ W3, const float* __restrict__ b3,
    float* __restrict__ out)
{
  __shared__ __align__(16) u8 smem[SMEM_BYTES];
  const int t = threadIdx.x;
  const int wt = blockIdx.x;
  const int rowbase = wt * 64;
  const int lane = t & 63;
  const int wv_ = t >> 6;
  const int colg = wv_ & 3, mg = wv_ >> 2;
  const int lr = lane & 15, hi = lane >> 4;
  const int cl = colg*16 + lr;

  attn_phase(smem, x, rowbase, wEmb, be, bk1, bk2, wV, bv, wrow, t, cl, lr, hi, mg);

  // GEMM1: h1 = relu(W1s . [e_q | atten] + b1eff); 2 out-halves x 2 K-chunks
  s16x4 h1f[2][4];
  #pragma unroll
  for (int oh = 0; oh < 2; ++oh) {
    f32x4 acc[4];
    #pragma unroll
    for (int m = 0; m < 4; ++m) acc[m] = {0.f,0.f,0.f,0.f};
    stage_w128(smem, W1s + oh*65536, 512, t);           // cols 0..255 (e_q)
    __syncthreads();
    #pragma unroll
    for (int ks = 0; ks < 8; ++ks) {
      s16x8 b = ldsB(smem, EQ_R, cl, ks, hi);
      #pragma unroll
      for (int m = 0; m < 4; ++m)
        acc[m] = __builtin_amdgcn_mfma_f32_16x16x32_bf16(
            ldsA(smem, mg*64 + m*16 + lr, ks, hi), b, acc[m], 0, 0, 0);
    }
    __syncthreads();
    stage_w128(smem, W1s + oh*65536 + 256, 512, t);     // cols 256..511 (atten)
    __syncthreads();
    #pragma unroll
    for (int ks = 0; ks < 8; ++ks) {
      s16x8 b = ldsB(smem, K1_R, cl, ks, hi);
      #pragma unroll
      for (int m = 0; m < 4; ++m)
        acc[m] = __builtin_amdgcn_mfma_f32_16x16x32_bf16(
            ldsA(smem, mg*64 + m*16 + lr, ks, hi), b, acc[m], 0, 0, 0);
    }
    __syncthreads();
    #pragma unroll
    for (int m = 0; m < 4; ++m) {
      f32x4 bb = ((const f32x4*)b1eff)[oh*32 + mg*16 + m*4 + hi];
      s16x4 p;
      #pragma unroll
      for (int r = 0; r < 4; ++r) {
        float v = acc[m][r] + bb[r];
        p[r] = (short)f2bf((v > 0.f) ? v : 0.f);
      }
      h1f[oh][m] = p;
    }
  }
  // h1 -> K2 region (e_k2 dead); stage wW2 concurrently (wbuf free)
  #pragma unroll
  for (int oh = 0; oh < 2; ++oh)
    #pragma unroll
    for (int m = 0; m < 4; ++m)
      *(s16x4*)(smem + K2_R + ((cl*512 + oh*256 + mg*128 + m*32 + hi*8) ^ ((cl & 7) << 4)))
          = h1f[oh][m];
  stage_w128(smem, wW2, 256, t);
  __syncthreads();

  // GEMM2: h2 = relu(W2 . h1 + b2), K=256
  f32x4 acc2[4];
  #pragma unroll
  for (int m = 0; m < 4; ++m) acc2[m] = {0.f,0.f,0.f,0.f};
  #pragma unroll
  for (int ks = 0; ks < 8; ++ks) {
    s16x8 b = ldsB(smem, K2_R, cl, ks, hi);
    #pragma unroll
    for (int m = 0; m < 4; ++m)
      acc2[m] = __builtin_amdgcn_mfma_f32_16x16x32_bf16(
          ldsA(smem, mg*64 + m*16 + lr, ks, hi), b, acc2[m], 0, 0, 0);
  }
  // h2 -> EQ region (e_q dead; EQ reads all barrier'd)
  #pragma unroll
  for (int m = 0; m < 4; ++m) {
    f32x4 bb = ((const f32x4*)b2)[mg*16 + m*4 + hi];
    s16x4 p;
    #pragma unroll
    for (int r = 0; r < 4; ++r) {
      float v = acc2[m][r] + bb[r];
      p[r] = (short)f2bf((v > 0.f) ? v : 0.f);
    }
    *(s16x4*)(smem + EQ_R + ((cl*512 + mg*128 + m*32 + hi*8) ^ ((cl & 7) << 4))) = p;
  }
  __syncthreads();

  // out = W3 . h2 + b3 (one thread per row)
  if (t < 64) {
    float s = b3[0];
    #pragma unroll
    for (int jj = 0; jj < 16; ++jj) {
      const u32x4 v = *(const u32x4*)(smem + EQ_R + ((t*512 + jj*16) ^ ((t & 7) << 4)));
      #pragma unroll
      for (int q2 = 0; q2 < 4; ++q2) {
        u32 u = v[q2];
        s += bf2f((u16)(u & 0xFFFFu)) * W3[jj*8 + q2*2];
        s += bf2f((u16)(u >> 16))     * W3[jj*8 + q2*2 + 1];
      }
    }
    out[rowbase + t] = s;
  }
}

extern "C" void kernel_launch(void* const* d_in, const int* in_sizes, int n_in,
                              void* d_out, int out_size, void* d_ws, size_t ws_size,
                              hipStream_t stream)
{
  const float* x   = (const float*)d_in[0];
  const float* We  = (const float*)d_in[1];
  const float* be  = (const float*)d_in[2];
  const float* Wk1 = (const float*)d_in[3];
  const float* bk1 = (const float*)d_in[4];
  const float* Wk2 = (const float*)d_in[5];
  const float* bk2 = (const float*)d_in[6];
  const float* Wq  = (const float*)d_in[7];
  const float* Wk  = (const float*)d_in[8];
  const float* Wv  = (const float*)d_in[9];
  const float* bv  = (const float*)d_in[10];
  const float* W1  = (const float*)d_in[11];
  const float* b1  = (const float*)d_in[12];
  const float* W2  = (const float*)d_in[13];
  const float* b2  = (const float*)d_in[14];
  const float* W3  = (const float*)d_in[15];
  const float* b3  = (const float*)d_in[16];

  u8* ws = (u8*)d_ws;
  float* pA    = (float*)(ws + PA_OFF);
  float* pB    = (float*)(ws + PB_OFF);
  float* qA    = (float*)(ws + QA_OFF);
  float* qB    = (float*)(ws + QB_OFF);
  float* mu    = (float*)(ws + MU_OFF);
  float* rstd  = (float*)(ws + RSTD_OFF);
  float* b1eff = (float*)(ws + B1E_OFF);
  u16*   wEmb  = (u16*)(ws + WEMB_OFF);
  u16*   wVb   = (u16*)(ws + WV_OFF);
  u16*   wW2   = (u16*)(ws + W2_OFF);
  u16*   wW1s  = (u16*)(ws + W1S_OFF);
  float* Wu    = (float*)(ws + WU_OFF);
  float* G     = (float*)(ws + G_OFF);
  float* g     = (float*)(ws + GG_OFF);
  float* scp   = (float*)(ws + SCP_OFF);
  float* wrow  = (float*)(ws + WROW_OFF);

  k0_convert<<<dim3(480), dim3(256), 0, stream>>>(We, Wk1, Wk2, Wv, W2, wEmb, wVb, wW2);
  k0b_wu<<<dim3(256), dim3(256), 0, stream>>>(Wq, Wk, Wu);
  k0c_G<<<dim3(2), dim3(256), 0, stream>>>(Wu, Wk1, bk1, Wk2, bk2, G, g);
  k0d_M<<<dim3(2), dim3(256), 0, stream>>>(We, be, G, g, scp);
  k0e_scores<<<dim3(1024), dim3(256), 0, stream>>>(x, scp, wrow);
  k1_attn<<<dim3(NTILE), dim3(512), 0, stream>>>(x, wEmb, be, bk1, bk2, wVb, bv, wrow, pA, pB);
  kR1_reduce<<<dim3(512), dim3(256), 0, stream>>>(pA, pB, qA, qB);
  kR2_stats<<<dim3(512), dim3(256), 0, stream>>>(qA, qB, mu, rstd);
  k2b_fold<<<dim3(256), dim3(256), 0, stream>>>(W1, b1, mu, rstd, wW1s, b1eff);
  k3_mlp<<<dim3(NTILE), dim3(512), 0, stream>>>(x, wEmb, be, bk1, bk2, wVb, bv, wrow,
                                                wW1s, b1eff, wW2, b2, W3, b3,
                                                (float*)d_out);
}